// Round 9
// baseline (5641.992 us; speedup 1.0000x reference)
//
#include <hip/hip_runtime.h>

#define NB 8
#define NPTS 8192
#define NC_FEAT 64
#define NS 2048
#define NK 32

typedef float v2f __attribute__((ext_vector_type(2)));

// Exact reference arithmetic for squared distance: no fma contraction,
// sum association ((dx^2 + dy^2) + dz^2) to match XLA's linear reduce.
__device__ __forceinline__ float d2_ref(float px, float py, float pz,
                                        float qx, float qy, float qz) {
  float dx = __fsub_rn(px, qx);
  float dy = __fsub_rn(py, qy);
  float dz = __fsub_rn(pz, qz);
  return __fadd_rn(__fadd_rn(__fmul_rn(dx, dx), __fmul_rn(dy, dy)),
                   __fmul_rn(dz, dz));
}

// DPP max-combine on packed u64 key. bound_ctrl=true -> OOB lanes give 0
// (dominated: every real key is > 0 since it>=1 occupies bits 13..23).
#define DPP_KEYMAX(key, ctrl)                                                 \
  {                                                                           \
    unsigned _lo = (unsigned)__builtin_amdgcn_update_dpp(                     \
        0, (int)(unsigned)(key), (ctrl), 0xf, 0xf, true);                     \
    unsigned _hi = (unsigned)__builtin_amdgcn_update_dpp(                     \
        0, (int)(unsigned)((key) >> 32), (ctrl), 0xf, 0xf, true);             \
    unsigned long long _o = ((unsigned long long)_hi << 32) | _lo;            \
    if (_o > (key)) (key) = _o;                                               \
  }
#define DPP_KEYMAX6(key)                                                      \
  DPP_KEYMAX(key, 0x111); DPP_KEYMAX(key, 0x112); DPP_KEYMAX(key, 0x114);     \
  DPP_KEYMAX(key, 0x118); DPP_KEYMAX(key, 0x142); DPP_KEYMAX(key, 0x143)

// ---------------------------------------------------------------------------
// Kernel 0: FPS across 8 CUs per batch (64 blocks x 256 threads).
// Each block stages the full cloud in LDS (96 KB); each wave owns 256
// contiguous points (4/lane). Per iteration: packed-asm distance update,
// 6-DPP wave argmax, then a BARRIER-FREE global handshake: wave writes one
// self-tagged key  dist[63:32] | it[23:13] | (8191-idx)[12:0]  to its LLC
// slot (relaxed agent atomic; the tag IS the ready flag), polls all 32
// batch slots until tag==it, and reduces them with 6 more DPP steps.
// Parity double-buffer (slot set it&1): a buffer is rewritten only at it+2,
// and reaching it+2 requires every wave posted it+1, i.e. left it -> no
// overwrite race. 0xAA ws poison has tag 1365 != {1,2} at first use. Keys
// of equal it compare as (dist, -orig_idx): exact jnp.argmax tie semantics.
// No __syncthreads in the loop.
// ---------------------------------------------------------------------------
__global__ __launch_bounds__(256)
void k_fps(const float* __restrict__ pos, float* __restrict__ new_xyz,
           unsigned long long* __restrict__ slots) {
#pragma clang fp contract(off)
  __shared__ __align__(16) float smem[3 * NPTS];  // 96 KB
  float* sx = smem;
  float* sy = smem + NPTS;
  float* sz = smem + 2 * NPTS;

  const int tid = threadIdx.x;
  const int b = blockIdx.x >> 3;   // batch
  const int blk = blockIdx.x & 7;  // sub-block within batch
  const int lane = tid & 63;
  const int wave = tid >> 6;            // 0..3
  const int wid = blk * 4 + wave;       // 0..31 within batch
  const float* p = pos + (size_t)b * NPTS * 3;
  unsigned long long* sb = slots + (size_t)b * 64;  // [2][32] per batch

  for (int i = tid; i < NPTS; i += 256) {
    sx[i] = p[3 * i + 0];
    sy[i] = p[3 * i + 1];
    sz[i] = p[3 * i + 2];
  }
  __syncthreads();

  // this lane's 4 contiguous points
  const int base = blk * 1024 + tid * 4;
  v2f px[2], py[2], pz[2], di[2];
#pragma unroll
  for (int k = 0; k < 2; ++k) {
    px[k] = *(const v2f*)&sx[base + 2 * k];
    py[k] = *(const v2f*)&sy[base + 2 * k];
    pz[k] = *(const v2f*)&sz[base + 2 * k];
    di[k] = (v2f){1e10f, 1e10f};
  }
  if (blk == 0 && tid == 0) {
    new_xyz[((size_t)b * NS) * 3 + 0] = sx[0];
    new_xyz[((size_t)b * NS) * 3 + 1] = sy[0];
    new_xyz[((size_t)b * NS) * 3 + 2] = sz[0];
  }

  int last = 0;
  for (int it = 1; it < NS; ++it) {
    float qx = sx[last], qy = sy[last], qz = sz[last];
    v2f nqx = (v2f){-qx, -qx};
    v2f nqy = (v2f){-qy, -qy};
    v2f nqz = (v2f){-qz, -qz};
    float bd = -1.0f;
    int bj = 0;
#pragma unroll
    for (int k = 0; k < 2; ++k) {
      v2f t0, t1, t2, d2v;
      // dx=px+(-qx); d2=((dx*dx+dy*dy)+dz*dz), packed dual-FP32, no fma.
      asm("v_pk_add_f32 %0, %4, %7\n\t"
          "v_pk_add_f32 %1, %5, %8\n\t"
          "v_pk_add_f32 %2, %6, %9\n\t"
          "v_pk_mul_f32 %0, %0, %0\n\t"
          "v_pk_mul_f32 %1, %1, %1\n\t"
          "v_pk_mul_f32 %2, %2, %2\n\t"
          "v_pk_add_f32 %3, %0, %1\n\t"
          "v_pk_add_f32 %3, %3, %2"
          : "=&v"(t0), "=&v"(t1), "=&v"(t2), "=&v"(d2v)
          : "v"(px[k]), "v"(py[k]), "v"(pz[k]), "v"(nqx), "v"(nqy), "v"(nqz));
      di[k] = __builtin_elementwise_min(di[k], d2v);
      if (di[k].x > bd) { bd = di[k].x; bj = 2 * k; }      // strict >:
      if (di[k].y > bd) { bd = di[k].y; bj = 2 * k + 1; }  // first max wins
    }
    unsigned long long key =
        ((unsigned long long)__float_as_uint(bd) << 32) |
        ((unsigned long long)(unsigned)(it & 0x7FF) << 13) |
        (unsigned long long)(unsigned)(8191 - (base + bj));
    DPP_KEYMAX6(key);  // wave max -> lane 63
    unsigned long long* pbuf = sb + (it & 1) * 32;
    if (lane == 63)
      __hip_atomic_store(&pbuf[wid], key, __ATOMIC_RELAXED,
                         __HIP_MEMORY_SCOPE_AGENT);
    // poll all 32 slots of this batch until every tag == it
    unsigned long long k2;
    const unsigned tgt = (unsigned)(it & 0x7FF);
    do {
      k2 = __hip_atomic_load(&pbuf[lane & 31], __ATOMIC_RELAXED,
                             __HIP_MEMORY_SCOPE_AGENT);
    } while (!__all((((unsigned)(k2 >> 13)) & 0x7FFu) == tgt));
    DPP_KEYMAX6(k2);  // both 32-lane halves hold the full set -> max @63
    int low = __builtin_amdgcn_readlane((int)(unsigned)k2, 63);
    int fi = 8191 - (int)((unsigned)low & 0x1FFFu);
    last = fi;
    if (blk == 0 && tid == 0) {
      new_xyz[((size_t)b * NS + it) * 3 + 0] = sx[fi];
      new_xyz[((size_t)b * NS + it) * 3 + 1] = sy[fi];
      new_xyz[((size_t)b * NS + it) * 3 + 2] = sz[fi];
    }
  }
}

// ---------------------------------------------------------------------------
// Kernel 1: blocks 0..1023 = feature transpose (B,C,N)->(B,N,C) 64x64 tiles;
//           block 1024    = weight transpose to [c][o] layout.
// ---------------------------------------------------------------------------
__global__ __launch_bounds__(256)
void k_tp(const float* __restrict__ feat, const float* __restrict__ w0,
          const float* __restrict__ w1, const float* __restrict__ w2,
          float* __restrict__ featT, float* __restrict__ wT) {
  __shared__ float tile[64 * 65];
  const int tid = threadIdx.x;
  if (blockIdx.x < NB * (NPTS / 64)) {
    const int t = blockIdx.x;
    const int b = t >> 7;           // t / 128
    const int n0 = (t & 127) << 6;  // *64
    const int col = tid & 63;
    const int r0 = tid >> 6;  // 0..3
#pragma unroll
    for (int q = 0; q < 16; ++q) {
      int c = r0 + q * 4;
      tile[c * 65 + col] = feat[((size_t)b * NC_FEAT + c) * NPTS + n0 + col];
    }
    __syncthreads();
#pragma unroll
    for (int q = 0; q < 16; ++q) {
      int r = r0 + q * 4;
      featT[((size_t)b * NPTS + n0 + r) * 64 + col] = tile[col * 65 + r];
    }
  } else {
    for (int i = tid; i < 67 * 64; i += 256)
      wT[i] = w0[(i & 63) * 67 + (i >> 6)];
    for (int i = tid; i < 64 * 64; i += 256)
      wT[67 * 64 + i] = w1[(i & 63) * 64 + (i >> 6)];
    for (int i = tid; i < 64 * 128; i += 256)
      wT[67 * 64 + 64 * 64 + i] = w2[(i & 127) * 64 + (i >> 7)];
  }
}

// ---------------------------------------------------------------------------
// Kernel 2: ball query. One wave per query point; first-32-hits via ballot.
// ---------------------------------------------------------------------------
__global__ __launch_bounds__(256)
void k_ball(const float* __restrict__ pos, const float* __restrict__ nxyz,
            int* __restrict__ ballidx) {
  const int wid = (blockIdx.x * 256 + threadIdx.x) >> 6;  // global wave id
  const int lane = threadIdx.x & 63;
  const int b = wid >> 11;
  const float qx = nxyz[wid * 3 + 0];
  const float qy = nxyz[wid * 3 + 1];
  const float qz = nxyz[wid * 3 + 2];
  const float* p = pos + (size_t)b * NPTS * 3;
  int* outp = ballidx + (size_t)wid * NK;

  int cnt = 0;
  int firstidx = 0x7fffffff;
  for (int n0 = 0; n0 < NPTS; n0 += 64) {
    const int i = n0 + lane;
    float d2 = d2_ref(p[3 * i], p[3 * i + 1], p[3 * i + 2], qx, qy, qz);
    bool hit = d2 < 0.25f;
    unsigned long long mask = __ballot(hit);
    int pre = __popcll(mask & ((1ull << lane) - 1ull));
    int slot = cnt + pre;
    if (hit && slot < NK) outp[slot] = i;
    if (hit && slot == 0) firstidx = i;
    cnt += __popcll(mask);
    if (cnt >= NK) break;
  }
#pragma unroll
  for (int m = 32; m >= 1; m >>= 1)
    firstidx = min(firstidx, __shfl_xor(firstidx, m, 64));
  int pad = (firstidx == 0x7fffffff) ? 0 : firstidx;
  int start = cnt < NK ? cnt : NK;
  if (lane < NK && lane >= start) outp[lane] = pad;
}

// ---------------------------------------------------------------------------
// Kernel 3: gather + 3-layer MLP + max over k. One thread per (b,s,k) sample.
// Per-thread column in LDS (stride 256 -> conflict-free), weights read as
// wave-uniform float4 broadcasts from pre-transposed wT.
// ---------------------------------------------------------------------------
#define MLP_FMA16(wr, xc, acc)                                   \
  _Pragma("unroll") for (int o4 = 0; o4 < 16; ++o4) {            \
    float4 w = (wr)[o4];                                         \
    (acc)[o4 * 4 + 0] = fmaf(w.x, (xc), (acc)[o4 * 4 + 0]);      \
    (acc)[o4 * 4 + 1] = fmaf(w.y, (xc), (acc)[o4 * 4 + 1]);      \
    (acc)[o4 * 4 + 2] = fmaf(w.z, (xc), (acc)[o4 * 4 + 2]);      \
    (acc)[o4 * 4 + 3] = fmaf(w.w, (xc), (acc)[o4 * 4 + 3]);      \
  }

__global__ __launch_bounds__(256)
void k_mlp(const float* __restrict__ pos, const float* __restrict__ featT,
           const float* __restrict__ wT, const float* __restrict__ b0,
           const float* __restrict__ b1, const float* __restrict__ b2,
           const int* __restrict__ ballidx, const float* __restrict__ nxyz,
           float* __restrict__ outf) {
  __shared__ float xs[64 * 256];  // 64 KB: per-thread column, stride 256
  const int tid = threadIdx.x;
  const int g = blockIdx.x * 256 + tid;
  const int s = (g >> 5) & (NS - 1);
  const int b = g >> 16;

  const int idx = ballidx[g];
  const float qx = nxyz[((size_t)b * NS + s) * 3 + 0];
  const float qy = nxyz[((size_t)b * NS + s) * 3 + 1];
  const float qz = nxyz[((size_t)b * NS + s) * 3 + 2];
  const float* pp = pos + ((size_t)b * NPTS + idx) * 3;
  const float x0 = __fsub_rn(pp[0], qx);
  const float x1 = __fsub_rn(pp[1], qy);
  const float x2 = __fsub_rn(pp[2], qz);

  const float4* fT = (const float4*)(featT + ((size_t)b * NPTS + idx) * 64);
#pragma unroll
  for (int c4 = 0; c4 < 16; ++c4) {
    float4 v = fT[c4];
    xs[(c4 * 4 + 0) * 256 + tid] = v.x;
    xs[(c4 * 4 + 1) * 256 + tid] = v.y;
    xs[(c4 * 4 + 2) * 256 + tid] = v.z;
    xs[(c4 * 4 + 3) * 256 + tid] = v.w;
  }

  const float* wt0 = wT;
  const float* wt1 = wT + 67 * 64;
  const float* wt2 = wT + 67 * 64 + 64 * 64;

  float acc[64];
  // ---------------- layer 0: 67 -> 64 ----------------
#pragma unroll
  for (int o = 0; o < 64; ++o) acc[o] = b0[o];
  {
    const float xr0 = x0, xr1 = x1, xr2 = x2;
    const float4* wr;
    wr = (const float4*)(wt0 + 0 * 64); MLP_FMA16(wr, xr0, acc);
    wr = (const float4*)(wt0 + 1 * 64); MLP_FMA16(wr, xr1, acc);
    wr = (const float4*)(wt0 + 2 * 64); MLP_FMA16(wr, xr2, acc);
  }
  for (int c = 0; c < 64; ++c) {
    float xc = xs[c * 256 + tid];
    const float4* wr = (const float4*)(wt0 + (3 + c) * 64);
    MLP_FMA16(wr, xc, acc);
  }
#pragma unroll
  for (int o = 0; o < 64; ++o) xs[o * 256 + tid] = fmaxf(acc[o], 0.0f);

  // ---------------- layer 1: 64 -> 64 ----------------
#pragma unroll
  for (int o = 0; o < 64; ++o) acc[o] = b1[o];
  for (int c = 0; c < 64; ++c) {
    float xc = xs[c * 256 + tid];
    const float4* wr = (const float4*)(wt1 + c * 64);
    MLP_FMA16(wr, xc, acc);
  }
#pragma unroll
  for (int o = 0; o < 64; ++o) xs[o * 256 + tid] = fmaxf(acc[o], 0.0f);

  // ---------------- layer 2: 64 -> 128 (two halves) + max over k ----------
#pragma unroll
  for (int h = 0; h < 2; ++h) {
#pragma unroll
    for (int o = 0; o < 64; ++o) acc[o] = b2[h * 64 + o];
    for (int c = 0; c < 64; ++c) {
      float xc = xs[c * 256 + tid];
      const float4* wr = (const float4*)(wt2 + c * 128 + h * 64);
      MLP_FMA16(wr, xc, acc);
    }
#pragma unroll
    for (int o = 0; o < 64; ++o) {
      float v = fmaxf(acc[o], 0.0f);
      v = fmaxf(v, __shfl_xor(v, 16, 64));
      v = fmaxf(v, __shfl_xor(v, 8, 64));
      v = fmaxf(v, __shfl_xor(v, 4, 64));
      v = fmaxf(v, __shfl_xor(v, 2, 64));
      v = fmaxf(v, __shfl_xor(v, 1, 64));
      if ((tid & 31) == 0)
        outf[((size_t)b * 128 + h * 64 + o) * NS + s] = v;
    }
  }
}

// ---------------------------------------------------------------------------
extern "C" void kernel_launch(void* const* d_in, const int* in_sizes, int n_in,
                              void* d_out, int out_size, void* d_ws,
                              size_t ws_size, hipStream_t stream) {
  const float* pos = (const float*)d_in[0];
  const float* feat = (const float*)d_in[1];
  const float* w0 = (const float*)d_in[2];
  const float* b0 = (const float*)d_in[3];
  const float* w1 = (const float*)d_in[4];
  const float* b1 = (const float*)d_in[5];
  const float* w2 = (const float*)d_in[6];
  const float* b2 = (const float*)d_in[7];

  float* out = (float*)d_out;
  float* new_xyz = out;                         // (B, S, 3)
  float* new_feat = out + (size_t)NB * NS * 3;  // (B, 128, S)

  // ws layout: slots u64[8][2][32] (4 KB) | ballidx (2 MB) | featT | wT
  unsigned long long* slots = (unsigned long long*)d_ws;
  int* ballidx = (int*)((char*)d_ws + 4096);
  float* featT = (float*)((char*)d_ws + 4096 + (size_t)NB * NS * NK * 4);
  float* wT = featT + (size_t)NB * NPTS * 64;  // 16576 floats

  // transpose (featT, wT) -- tiny, independent of FPS
  hipLaunchKernelGGL(k_tp, dim3(NB * (NPTS / 64) + 1), dim3(256), 0, stream,
                     feat, w0, w1, w2, featT, wT);
  // FPS: 8 blocks per batch, tagged-key LLC handshake
  hipLaunchKernelGGL(k_fps, dim3(NB * 8), dim3(256), 0, stream, pos, new_xyz,
                     slots);
  // ball query: one wave per (b,s)
  hipLaunchKernelGGL(k_ball, dim3((NB * NS) / 4), dim3(256), 0, stream, pos,
                     new_xyz, ballidx);
  // gather + MLP + max-k
  hipLaunchKernelGGL(k_mlp, dim3((NB * NS * NK) / 256), dim3(256), 0, stream,
                     pos, featT, wT, b0, b1, b2, ballidx, new_xyz, new_feat);
}

// Round 10
// 2580.006 us; speedup vs baseline: 2.1868x; 2.1868x over previous
//
#include <hip/hip_runtime.h>

#define NB 8
#define NPTS 8192
#define NC_FEAT 64
#define NS 2048
#define NK 32

typedef float v2f __attribute__((ext_vector_type(2)));

// Exact reference arithmetic for squared distance: no fma contraction,
// sum association ((dx^2 + dy^2) + dz^2) to match XLA's linear reduce.
__device__ __forceinline__ float d2_ref(float px, float py, float pz,
                                        float qx, float qy, float qz) {
  float dx = __fsub_rn(px, qx);
  float dy = __fsub_rn(py, qy);
  float dz = __fsub_rn(pz, qz);
  return __fadd_rn(__fadd_rn(__fmul_rn(dx, dx), __fmul_rn(dy, dy)),
                   __fmul_rn(dz, dz));
}

// DPP max-combine on packed u64 key. bound_ctrl=true -> OOB lanes give 0.
#define DPP_KEYMAX(key, ctrl)                                                 \
  {                                                                           \
    unsigned _lo = (unsigned)__builtin_amdgcn_update_dpp(                     \
        0, (int)(unsigned)(key), (ctrl), 0xf, 0xf, true);                     \
    unsigned _hi = (unsigned)__builtin_amdgcn_update_dpp(                     \
        0, (int)(unsigned)((key) >> 32), (ctrl), 0xf, 0xf, true);             \
    unsigned long long _o = ((unsigned long long)_hi << 32) | _lo;            \
    if (_o > (key)) (key) = _o;                                               \
  }

// ---------------------------------------------------------------------------
// Kernel 0: FPS. One 512-thread block per batch (2 waves/SIMD hide DPP/LDS
// stalls), 16 contiguous points per lane. Distance update = r8's verified
// packed dual-FP32 asm (8 inst / 2 pts; px+(-qx) is bit-identical to sub;
// association ((xx+yy)+zz) preserved; no fma). Argmax = fmax tree + one
// descending ==-scan (lowest j wins = first-occurrence), then the r5/r6-
// proven u64 (dist<<32 | ~idx) DPP reduce + single-barrier rk[2][16]
// cross-wave handshake. Exact jnp.argmax semantics.
// ---------------------------------------------------------------------------
__global__ __launch_bounds__(512)
void k_fps(const float* __restrict__ pos, float* __restrict__ new_xyz) {
#pragma clang fp contract(off)
  __shared__ __align__(16) float smem[3 * NPTS + 64];
  float* sx = smem;
  float* sy = smem + NPTS;
  float* sz = smem + 2 * NPTS;
  unsigned long long* rk = (unsigned long long*)(smem + 3 * NPTS);  // [2][16]

  const int tid = threadIdx.x;
  const int b = blockIdx.x;
  const float* p = pos + (size_t)b * NPTS * 3;

  for (int i = tid; i < NPTS; i += 512) {
    sx[i] = p[3 * i + 0];
    sy[i] = p[3 * i + 1];
    sz[i] = p[3 * i + 2];
  }
  if (tid < 32) rk[tid] = 0ull;  // zero both buffers; slots 8..15 stay 0
  __syncthreads();

  const int base = tid * 16;
  v2f px[8], py[8], pz[8], di[8];
#pragma unroll
  for (int k = 0; k < 8; ++k) {
    px[k] = *(const v2f*)&sx[base + 2 * k];
    py[k] = *(const v2f*)&sy[base + 2 * k];
    pz[k] = *(const v2f*)&sz[base + 2 * k];
    di[k] = (v2f){1e10f, 1e10f};
  }
  if (tid == 0) {
    new_xyz[((size_t)b * NS) * 3 + 0] = sx[0];
    new_xyz[((size_t)b * NS) * 3 + 1] = sy[0];
    new_xyz[((size_t)b * NS) * 3 + 2] = sz[0];
  }

  const int lane = tid & 63;
  const int wave = tid >> 6;
  int last = 0, buf = 0;

  for (int it = 1; it < NS; ++it) {
    float qx = sx[last], qy = sy[last], qz = sz[last];
    v2f nqx = (v2f){-qx, -qx};
    v2f nqy = (v2f){-qy, -qy};
    v2f nqz = (v2f){-qz, -qz};
    // packed-asm distance + scalar min (no argmax bookkeeping in the loop)
#pragma unroll
    for (int k = 0; k < 8; ++k) {
      v2f t0, t1, t2, d2v;
      asm("v_pk_add_f32 %0, %4, %7\n\t"
          "v_pk_add_f32 %1, %5, %8\n\t"
          "v_pk_add_f32 %2, %6, %9\n\t"
          "v_pk_mul_f32 %0, %0, %0\n\t"
          "v_pk_mul_f32 %1, %1, %1\n\t"
          "v_pk_mul_f32 %2, %2, %2\n\t"
          "v_pk_add_f32 %3, %0, %1\n\t"
          "v_pk_add_f32 %3, %3, %2"
          : "=&v"(t0), "=&v"(t1), "=&v"(t2), "=&v"(d2v)
          : "v"(px[k]), "v"(py[k]), "v"(pz[k]), "v"(nqx), "v"(nqy), "v"(nqz));
      di[k].x = fminf(di[k].x, d2v.x);
      di[k].y = fminf(di[k].y, d2v.y);
    }
    // per-lane max (fmax tree; max3-fusable)
    float h0 = fmaxf(fmaxf(di[0].x, di[0].y), fmaxf(di[1].x, di[1].y));
    float h1 = fmaxf(fmaxf(di[2].x, di[2].y), fmaxf(di[3].x, di[3].y));
    float h2 = fmaxf(fmaxf(di[4].x, di[4].y), fmaxf(di[5].x, di[5].y));
    float h3 = fmaxf(fmaxf(di[6].x, di[6].y), fmaxf(di[7].x, di[7].y));
    float bd = fmaxf(fmaxf(h0, h1), fmaxf(h2, h3));
    // descending ==-scan: final bj = lowest j with di==bd (first occurrence)
    int bj = 0;
#pragma unroll
    for (int j = 15; j >= 0; --j) {
      float v = (j & 1) ? di[j >> 1].y : di[j >> 1].x;
      if (v == bd) bj = j;
    }
    unsigned long long key =
        ((unsigned long long)__float_as_uint(bd) << 32) |
        (unsigned)~(unsigned)(base + bj);
    // wave-level max via DPP: row_shr 1/2/4/8, bcast15, bcast31 -> lane63
    DPP_KEYMAX(key, 0x111);
    DPP_KEYMAX(key, 0x112);
    DPP_KEYMAX(key, 0x114);
    DPP_KEYMAX(key, 0x118);
    DPP_KEYMAX(key, 0x142);
    DPP_KEYMAX(key, 0x143);
    if (lane == 63) rk[buf * 16 + wave] = key;
    __syncthreads();
    // cross-wave: 8 partials (+8 zero pads); 4 DPP steps into lane 15
    key = rk[buf * 16 + (lane & 15)];
    DPP_KEYMAX(key, 0x111);
    DPP_KEYMAX(key, 0x112);
    DPP_KEYMAX(key, 0x114);
    DPP_KEYMAX(key, 0x118);
    int fi = (int)~(unsigned)__builtin_amdgcn_readlane((int)(unsigned)key, 15);
    last = fi;
    buf ^= 1;
    if (tid == 0) {
      new_xyz[((size_t)b * NS + it) * 3 + 0] = sx[fi];
      new_xyz[((size_t)b * NS + it) * 3 + 1] = sy[fi];
      new_xyz[((size_t)b * NS + it) * 3 + 2] = sz[fi];
    }
  }
}

// ---------------------------------------------------------------------------
// Kernel 1: blocks 0..1023 = feature transpose (B,C,N)->(B,N,C) 64x64 tiles;
//           block 1024    = weight transpose to [c][o] layout.
// ---------------------------------------------------------------------------
__global__ __launch_bounds__(256)
void k_tp(const float* __restrict__ feat, const float* __restrict__ w0,
          const float* __restrict__ w1, const float* __restrict__ w2,
          float* __restrict__ featT, float* __restrict__ wT) {
  __shared__ float tile[64 * 65];
  const int tid = threadIdx.x;
  if (blockIdx.x < NB * (NPTS / 64)) {
    const int t = blockIdx.x;
    const int b = t >> 7;           // t / 128
    const int n0 = (t & 127) << 6;  // *64
    const int col = tid & 63;
    const int r0 = tid >> 6;  // 0..3
#pragma unroll
    for (int q = 0; q < 16; ++q) {
      int c = r0 + q * 4;
      tile[c * 65 + col] = feat[((size_t)b * NC_FEAT + c) * NPTS + n0 + col];
    }
    __syncthreads();
#pragma unroll
    for (int q = 0; q < 16; ++q) {
      int r = r0 + q * 4;
      featT[((size_t)b * NPTS + n0 + r) * 64 + col] = tile[col * 65 + r];
    }
  } else {
    for (int i = tid; i < 67 * 64; i += 256)
      wT[i] = w0[(i & 63) * 67 + (i >> 6)];
    for (int i = tid; i < 64 * 64; i += 256)
      wT[67 * 64 + i] = w1[(i & 63) * 64 + (i >> 6)];
    for (int i = tid; i < 64 * 128; i += 256)
      wT[67 * 64 + 64 * 64 + i] = w2[(i & 127) * 64 + (i >> 7)];
  }
}

// ---------------------------------------------------------------------------
// Kernel 2: ball query. One wave per query point; first-32-hits via ballot.
// ---------------------------------------------------------------------------
__global__ __launch_bounds__(256)
void k_ball(const float* __restrict__ pos, const float* __restrict__ nxyz,
            int* __restrict__ ballidx) {
  const int wid = (blockIdx.x * 256 + threadIdx.x) >> 6;  // global wave id
  const int lane = threadIdx.x & 63;
  const int b = wid >> 11;
  const float qx = nxyz[wid * 3 + 0];
  const float qy = nxyz[wid * 3 + 1];
  const float qz = nxyz[wid * 3 + 2];
  const float* p = pos + (size_t)b * NPTS * 3;
  int* outp = ballidx + (size_t)wid * NK;

  int cnt = 0;
  int firstidx = 0x7fffffff;
  for (int n0 = 0; n0 < NPTS; n0 += 64) {
    const int i = n0 + lane;
    float d2 = d2_ref(p[3 * i], p[3 * i + 1], p[3 * i + 2], qx, qy, qz);
    bool hit = d2 < 0.25f;
    unsigned long long mask = __ballot(hit);
    int pre = __popcll(mask & ((1ull << lane) - 1ull));
    int slot = cnt + pre;
    if (hit && slot < NK) outp[slot] = i;
    if (hit && slot == 0) firstidx = i;
    cnt += __popcll(mask);
    if (cnt >= NK) break;
  }
#pragma unroll
  for (int m = 32; m >= 1; m >>= 1)
    firstidx = min(firstidx, __shfl_xor(firstidx, m, 64));
  int pad = (firstidx == 0x7fffffff) ? 0 : firstidx;
  int start = cnt < NK ? cnt : NK;
  if (lane < NK && lane >= start) outp[lane] = pad;
}

// ---------------------------------------------------------------------------
// Kernel 3: gather + 3-layer MLP + max over k. One thread per (b,s,k) sample.
// Per-thread column in LDS (stride 256 -> conflict-free), weights read as
// wave-uniform float4 broadcasts from pre-transposed wT.
// ---------------------------------------------------------------------------
#define MLP_FMA16(wr, xc, acc)                                   \
  _Pragma("unroll") for (int o4 = 0; o4 < 16; ++o4) {            \
    float4 w = (wr)[o4];                                         \
    (acc)[o4 * 4 + 0] = fmaf(w.x, (xc), (acc)[o4 * 4 + 0]);      \
    (acc)[o4 * 4 + 1] = fmaf(w.y, (xc), (acc)[o4 * 4 + 1]);      \
    (acc)[o4 * 4 + 2] = fmaf(w.z, (xc), (acc)[o4 * 4 + 2]);      \
    (acc)[o4 * 4 + 3] = fmaf(w.w, (xc), (acc)[o4 * 4 + 3]);      \
  }

__global__ __launch_bounds__(256)
void k_mlp(const float* __restrict__ pos, const float* __restrict__ featT,
           const float* __restrict__ wT, const float* __restrict__ b0,
           const float* __restrict__ b1, const float* __restrict__ b2,
           const int* __restrict__ ballidx, const float* __restrict__ nxyz,
           float* __restrict__ outf) {
  __shared__ float xs[64 * 256];  // 64 KB: per-thread column, stride 256
  const int tid = threadIdx.x;
  const int g = blockIdx.x * 256 + tid;
  const int s = (g >> 5) & (NS - 1);
  const int b = g >> 16;

  const int idx = ballidx[g];
  const float qx = nxyz[((size_t)b * NS + s) * 3 + 0];
  const float qy = nxyz[((size_t)b * NS + s) * 3 + 1];
  const float qz = nxyz[((size_t)b * NS + s) * 3 + 2];
  const float* pp = pos + ((size_t)b * NPTS + idx) * 3;
  const float x0 = __fsub_rn(pp[0], qx);
  const float x1 = __fsub_rn(pp[1], qy);
  const float x2 = __fsub_rn(pp[2], qz);

  const float4* fT = (const float4*)(featT + ((size_t)b * NPTS + idx) * 64);
#pragma unroll
  for (int c4 = 0; c4 < 16; ++c4) {
    float4 v = fT[c4];
    xs[(c4 * 4 + 0) * 256 + tid] = v.x;
    xs[(c4 * 4 + 1) * 256 + tid] = v.y;
    xs[(c4 * 4 + 2) * 256 + tid] = v.z;
    xs[(c4 * 4 + 3) * 256 + tid] = v.w;
  }

  const float* wt0 = wT;
  const float* wt1 = wT + 67 * 64;
  const float* wt2 = wT + 67 * 64 + 64 * 64;

  float acc[64];
  // ---------------- layer 0: 67 -> 64 ----------------
#pragma unroll
  for (int o = 0; o < 64; ++o) acc[o] = b0[o];
  {
    const float xr0 = x0, xr1 = x1, xr2 = x2;
    const float4* wr;
    wr = (const float4*)(wt0 + 0 * 64); MLP_FMA16(wr, xr0, acc);
    wr = (const float4*)(wt0 + 1 * 64); MLP_FMA16(wr, xr1, acc);
    wr = (const float4*)(wt0 + 2 * 64); MLP_FMA16(wr, xr2, acc);
  }
  for (int c = 0; c < 64; ++c) {
    float xc = xs[c * 256 + tid];
    const float4* wr = (const float4*)(wt0 + (3 + c) * 64);
    MLP_FMA16(wr, xc, acc);
  }
#pragma unroll
  for (int o = 0; o < 64; ++o) xs[o * 256 + tid] = fmaxf(acc[o], 0.0f);

  // ---------------- layer 1: 64 -> 64 ----------------
#pragma unroll
  for (int o = 0; o < 64; ++o) acc[o] = b1[o];
  for (int c = 0; c < 64; ++c) {
    float xc = xs[c * 256 + tid];
    const float4* wr = (const float4*)(wt1 + c * 64);
    MLP_FMA16(wr, xc, acc);
  }
#pragma unroll
  for (int o = 0; o < 64; ++o) xs[o * 256 + tid] = fmaxf(acc[o], 0.0f);

  // ---------------- layer 2: 64 -> 128 (two halves) + max over k ----------
#pragma unroll
  for (int h = 0; h < 2; ++h) {
#pragma unroll
    for (int o = 0; o < 64; ++o) acc[o] = b2[h * 64 + o];
    for (int c = 0; c < 64; ++c) {
      float xc = xs[c * 256 + tid];
      const float4* wr = (const float4*)(wt2 + c * 128 + h * 64);
      MLP_FMA16(wr, xc, acc);
    }
#pragma unroll
    for (int o = 0; o < 64; ++o) {
      float v = fmaxf(acc[o], 0.0f);
      v = fmaxf(v, __shfl_xor(v, 16, 64));
      v = fmaxf(v, __shfl_xor(v, 8, 64));
      v = fmaxf(v, __shfl_xor(v, 4, 64));
      v = fmaxf(v, __shfl_xor(v, 2, 64));
      v = fmaxf(v, __shfl_xor(v, 1, 64));
      if ((tid & 31) == 0)
        outf[((size_t)b * 128 + h * 64 + o) * NS + s] = v;
    }
  }
}

// ---------------------------------------------------------------------------
extern "C" void kernel_launch(void* const* d_in, const int* in_sizes, int n_in,
                              void* d_out, int out_size, void* d_ws,
                              size_t ws_size, hipStream_t stream) {
  const float* pos = (const float*)d_in[0];
  const float* feat = (const float*)d_in[1];
  const float* w0 = (const float*)d_in[2];
  const float* b0 = (const float*)d_in[3];
  const float* w1 = (const float*)d_in[4];
  const float* b1 = (const float*)d_in[5];
  const float* w2 = (const float*)d_in[6];
  const float* b2 = (const float*)d_in[7];

  float* out = (float*)d_out;
  float* new_xyz = out;                         // (B, S, 3)
  float* new_feat = out + (size_t)NB * NS * 3;  // (B, 128, S)

  int* ballidx = (int*)d_ws;                                    // B*S*K ints
  float* featT = (float*)d_ws + (size_t)NB * NS * NK;           // B*N*64
  float* wT = featT + (size_t)NB * NPTS * 64;                   // 16576 floats

  // transpose (featT, wT) -- tiny, independent of FPS
  hipLaunchKernelGGL(k_tp, dim3(NB * (NPTS / 64) + 1), dim3(256), 0, stream,
                     feat, w0, w1, w2, featT, wT);
  // FPS: one 512-thread block per batch, packed-asm distances
  hipLaunchKernelGGL(k_fps, dim3(NB), dim3(512), 0, stream, pos, new_xyz);
  // ball query: one wave per (b,s)
  hipLaunchKernelGGL(k_ball, dim3((NB * NS) / 4), dim3(256), 0, stream, pos,
                     new_xyz, ballidx);
  // gather + MLP + max-k
  hipLaunchKernelGGL(k_mlp, dim3((NB * NS * NK) / 256), dim3(256), 0, stream,
                     pos, featT, wT, b0, b1, b2, ballidx, new_xyz, new_feat);
}

// Round 11
// 2342.267 us; speedup vs baseline: 2.4088x; 1.1015x over previous
//
#include <hip/hip_runtime.h>

#define NB 8
#define NPTS 8192
#define NC_FEAT 64
#define NS 2048
#define NK 32
#define NTASK (NB * NS)

typedef float v2f __attribute__((ext_vector_type(2)));

// ws byte offsets
#define WS_QUEUE 0
#define WS_PROG 64
#define WS_XY64 4096
#define WS_Z32 (4096 + 131072)
#define WS_FEATT (4096 + 131072 + 65536)
#define WS_WT (WS_FEATT + (size_t)NB * NPTS * 64 * 4)

// Exact reference arithmetic: no fma, ((dx^2+dy^2)+dz^2) association.
__device__ __forceinline__ float d2_ref(float px, float py, float pz,
                                        float qx, float qy, float qz) {
  float dx = __fsub_rn(px, qx);
  float dy = __fsub_rn(py, qy);
  float dz = __fsub_rn(pz, qz);
  return __fadd_rn(__fadd_rn(__fmul_rn(dx, dx), __fmul_rn(dy, dy)),
                   __fmul_rn(dz, dz));
}

#define DPP_KEYMAX(key, ctrl)                                                 \
  {                                                                           \
    unsigned _lo = (unsigned)__builtin_amdgcn_update_dpp(                     \
        0, (int)(unsigned)(key), (ctrl), 0xf, 0xf, true);                     \
    unsigned _hi = (unsigned)__builtin_amdgcn_update_dpp(                     \
        0, (int)(unsigned)((key) >> 32), (ctrl), 0xf, 0xf, true);             \
    unsigned long long _o = ((unsigned long long)_hi << 32) | _lo;            \
    if (_o > (key)) (key) = _o;                                               \
  }

#define MLP_FMA16(wr, xc, acc)                                   \
  _Pragma("unroll") for (int o4 = 0; o4 < 16; ++o4) {            \
    float4 w = (wr)[o4];                                         \
    (acc)[o4 * 4 + 0] = fmaf(w.x, (xc), (acc)[o4 * 4 + 0]);      \
    (acc)[o4 * 4 + 1] = fmaf(w.y, (xc), (acc)[o4 * 4 + 1]);      \
    (acc)[o4 * 4 + 2] = fmaf(w.z, (xc), (acc)[o4 * 4 + 2]);      \
    (acc)[o4 * 4 + 3] = fmaf(w.w, (xc), (acc)[o4 * 4 + 3]);      \
  }

// ---------------------------------------------------------------------------
// k_tp: feature transpose + weight transpose + ctrl zeroing (runs BEFORE the
// fused kernel on the stream, so queue/progress are zero despite ws poison).
// ---------------------------------------------------------------------------
__global__ __launch_bounds__(256)
void k_tp(const float* __restrict__ feat, const float* __restrict__ w0,
          const float* __restrict__ w1, const float* __restrict__ w2,
          char* __restrict__ ws) {
  __shared__ float tile[64 * 65];
  float* featT = (float*)(ws + WS_FEATT);
  float* wT = (float*)(ws + WS_WT);
  const int tid = threadIdx.x;
  if (blockIdx.x < NB * (NPTS / 64)) {
    const int t = blockIdx.x;
    const int b = t >> 7;
    const int n0 = (t & 127) << 6;
    const int col = tid & 63;
    const int r0 = tid >> 6;
#pragma unroll
    for (int q = 0; q < 16; ++q) {
      int c = r0 + q * 4;
      tile[c * 65 + col] = feat[((size_t)b * NC_FEAT + c) * NPTS + n0 + col];
    }
    __syncthreads();
#pragma unroll
    for (int q = 0; q < 16; ++q) {
      int r = r0 + q * 4;
      featT[((size_t)b * NPTS + n0 + r) * 64 + col] = tile[col * 65 + r];
    }
  } else {
    if (tid < 24) ((int*)ws)[tid] = 0;  // queue + progress[8] (within 96B)
    for (int i = tid; i < 67 * 64; i += 256)
      wT[i] = w0[(i & 63) * 67 + (i >> 6)];
    for (int i = tid; i < 64 * 64; i += 256)
      wT[67 * 64 + i] = w1[(i & 63) * 64 + (i >> 6)];
    for (int i = tid; i < 64 * 128; i += 256)
      wT[67 * 64 + 64 * 64 + i] = w2[(i & 127) * 64 + (i >> 7)];
  }
}

// ---------------------------------------------------------------------------
// Fused kernel: 256 blocks x 512 threads, all co-resident (1 block/CU).
// Blocks 0..7: r6-proven FPS (one per batch) + LLC mirror + progress release.
// Blocks 8..255: workers -- grab 16 tasks (all 8 batches x 2 samples), wait
// for progress, ball query (8 waves x 2 tasks), MLP (2x256-thread groups).
// ---------------------------------------------------------------------------
__global__ __launch_bounds__(512)
void k_fused(const float* __restrict__ pos, const float* __restrict__ b0,
             const float* __restrict__ b1, const float* __restrict__ b2,
             char* __restrict__ ws, float* __restrict__ new_xyz,
             float* __restrict__ outf) {
#pragma clang fp contract(off)
  __shared__ __align__(16) float smf[33360];  // ~133.4 KB union
  int* queue = (int*)ws;
  int* progress = (int*)(ws + WS_PROG);
  unsigned long long* xy64 = (unsigned long long*)(ws + WS_XY64);
  unsigned* z32 = (unsigned*)(ws + WS_Z32);
  const float* featT = (const float*)(ws + WS_FEATT);
  const float* wT = (const float*)(ws + WS_WT);
  const int wtid = threadIdx.x;

  if (blockIdx.x < NB) {
    // =========================== FPS (r6 structure) ========================
    float* sx = smf;
    float* sy = smf + NPTS;
    float* sz = smf + 2 * NPTS;
    unsigned long long* rk = (unsigned long long*)(smf + 3 * NPTS);  // [2][16]
    const int tid = wtid;
    const int b = blockIdx.x;
    const float* p = pos + (size_t)b * NPTS * 3;

    for (int i = tid; i < NPTS; i += 512) {
      sx[i] = p[3 * i + 0];
      sy[i] = p[3 * i + 1];
      sz[i] = p[3 * i + 2];
    }
    if (tid < 32) rk[tid] = 0ull;
    __syncthreads();

    const int base = tid * 16;
    v2f px[8], py[8], pz[8], di[8];
#pragma unroll
    for (int k = 0; k < 8; ++k) {
      px[k] = *(const v2f*)&sx[base + 2 * k];
      py[k] = *(const v2f*)&sy[base + 2 * k];
      pz[k] = *(const v2f*)&sz[base + 2 * k];
      di[k] = (v2f){1e10f, 1e10f};
    }
    if (tid == 0) {
      new_xyz[((size_t)b * NS) * 3 + 0] = sx[0];
      new_xyz[((size_t)b * NS) * 3 + 1] = sy[0];
      new_xyz[((size_t)b * NS) * 3 + 2] = sz[0];
      unsigned long long xy = ((unsigned long long)__float_as_uint(sy[0]) << 32) |
                              __float_as_uint(sx[0]);
      __hip_atomic_store(&xy64[b * NS + 0], xy, __ATOMIC_RELAXED,
                         __HIP_MEMORY_SCOPE_AGENT);
      __hip_atomic_store(&z32[b * NS + 0], __float_as_uint(sz[0]),
                         __ATOMIC_RELAXED, __HIP_MEMORY_SCOPE_AGENT);
    }

    const int lane = tid & 63;
    const int wave = tid >> 6;
    int last = 0, buf = 0;

    for (int it = 1; it < NS; ++it) {
      float qx = sx[last], qy = sy[last], qz = sz[last];
#pragma unroll
      for (int k = 0; k < 8; ++k) {
        v2f dx = px[k] - qx;
        v2f dy = py[k] - qy;
        v2f dz = pz[k] - qz;
        v2f d2 = (dx * dx + dy * dy) + dz * dz;
        di[k] = __builtin_elementwise_min(di[k], d2);
      }
      v2f m0 = __builtin_elementwise_max(di[0], di[1]);
      v2f m1 = __builtin_elementwise_max(di[2], di[3]);
      v2f m2 = __builtin_elementwise_max(di[4], di[5]);
      v2f m3 = __builtin_elementwise_max(di[6], di[7]);
      v2f m4 = __builtin_elementwise_max(m0, m1);
      v2f m5 = __builtin_elementwise_max(m2, m3);
      v2f m6 = __builtin_elementwise_max(m4, m5);
      float bd = fmaxf(m6.x, m6.y);
      int bj = 0;
#pragma unroll
      for (int j = 15; j >= 0; --j) {
        float v = (j & 1) ? di[j >> 1].y : di[j >> 1].x;
        if (v == bd) bj = j;
      }
      unsigned long long key =
          ((unsigned long long)__float_as_uint(bd) << 32) |
          (unsigned)~(unsigned)(base + bj);
      DPP_KEYMAX(key, 0x111);
      DPP_KEYMAX(key, 0x112);
      DPP_KEYMAX(key, 0x114);
      DPP_KEYMAX(key, 0x118);
      DPP_KEYMAX(key, 0x142);
      DPP_KEYMAX(key, 0x143);
      if (lane == 63) rk[buf * 16 + wave] = key;
      __syncthreads();
      key = rk[buf * 16 + (lane & 15)];
      DPP_KEYMAX(key, 0x111);
      DPP_KEYMAX(key, 0x112);
      DPP_KEYMAX(key, 0x114);
      DPP_KEYMAX(key, 0x118);
      int fi = (int)~(unsigned)__builtin_amdgcn_readlane((int)(unsigned)key, 15);
      last = fi;
      buf ^= 1;
      if (tid == 0) {
        float fx = sx[fi], fy = sy[fi], fz = sz[fi];
        new_xyz[((size_t)b * NS + it) * 3 + 0] = fx;
        new_xyz[((size_t)b * NS + it) * 3 + 1] = fy;
        new_xyz[((size_t)b * NS + it) * 3 + 2] = fz;
        unsigned long long xy =
            ((unsigned long long)__float_as_uint(fy) << 32) | __float_as_uint(fx);
        __hip_atomic_store(&xy64[b * NS + it], xy, __ATOMIC_RELAXED,
                           __HIP_MEMORY_SCOPE_AGENT);
        __hip_atomic_store(&z32[b * NS + it], __float_as_uint(fz),
                           __ATOMIC_RELAXED, __HIP_MEMORY_SCOPE_AGENT);
        if ((it & 31) == 31)  // it=2047 hits this too -> final progress=2048
          __hip_atomic_store(&progress[b], it + 1, __ATOMIC_RELEASE,
                             __HIP_MEMORY_SCOPE_AGENT);
      }
    }
    return;
  }

  // ================================ workers ================================
  float* xs0 = smf;                         // [64*256] group 0
  int* sidx = (int*)(smf + 32768);          // [16][32]
  float* snx = smf + 32768 + 512;           // [16][4]
  int* sbase = (int*)(smf + 32768 + 512 + 64);
  const int lane = wtid & 63;
  const int w = wtid >> 6;  // wave 0..7

  for (;;) {
    if (wtid == 0) *sbase = atomicAdd(queue, 16);
    __syncthreads();
    const int base_t = *sbase;
    if (base_t >= NTASK) break;
    const int sEnd = ((base_t + 15) >> 3) + 1;  // need progress >= sEnd
    if (wtid < 64) {
      int pr;
      do {
        __builtin_amdgcn_s_sleep(2);
        pr = (lane < 8) ? __hip_atomic_load(&progress[lane], __ATOMIC_ACQUIRE,
                                            __HIP_MEMORY_SCOPE_AGENT)
                        : 0x7fffffff;
      } while (!__all(pr >= sEnd));
    }
    __syncthreads();
    if (wtid < 16) {
      int t = base_t + wtid, bb = t & 7, ss = t >> 3;
      unsigned long long xy = __hip_atomic_load(
          &xy64[bb * NS + ss], __ATOMIC_RELAXED, __HIP_MEMORY_SCOPE_AGENT);
      unsigned z = __hip_atomic_load(&z32[bb * NS + ss], __ATOMIC_RELAXED,
                                     __HIP_MEMORY_SCOPE_AGENT);
      snx[wtid * 4 + 0] = __uint_as_float((unsigned)xy);
      snx[wtid * 4 + 1] = __uint_as_float((unsigned)(xy >> 32));
      snx[wtid * 4 + 2] = __uint_as_float(z);
    }
    __syncthreads();
    // ---- ball query: wave w handles tasks 2w, 2w+1 ----
#pragma unroll
    for (int tt = 0; tt < 2; ++tt) {
      const int tl = w * 2 + tt;
      const int bb = (base_t + tl) & 7;
      const float qx = snx[tl * 4 + 0];
      const float qy = snx[tl * 4 + 1];
      const float qz = snx[tl * 4 + 2];
      const float* p = pos + (size_t)bb * NPTS * 3;
      int cnt = 0;
      int firstidx = 0x7fffffff;
      for (int n0 = 0; n0 < NPTS; n0 += 64) {
        const int i = n0 + lane;
        float d2 = d2_ref(p[3 * i], p[3 * i + 1], p[3 * i + 2], qx, qy, qz);
        bool hit = d2 < 0.25f;
        unsigned long long mask = __ballot(hit);
        int pre = __popcll(mask & ((1ull << lane) - 1ull));
        int slot = cnt + pre;
        if (hit && slot < NK) sidx[tl * 32 + slot] = i;
        if (hit && slot == 0) firstidx = i;
        cnt += __popcll(mask);
        if (cnt >= NK) break;
      }
#pragma unroll
      for (int m = 32; m >= 1; m >>= 1)
        firstidx = min(firstidx, __shfl_xor(firstidx, m, 64));
      int pad = (firstidx == 0x7fffffff) ? 0 : firstidx;
      int start = cnt < NK ? cnt : NK;
      if (lane < NK && lane >= start) sidx[tl * 32 + lane] = pad;
    }
    __syncthreads();
    // ---- MLP: two 256-thread groups, 8 tasks each ----
    {
      const int grp = wtid >> 8;
      const int tidl = wtid & 255;
      const int tl = grp * 8 + (tidl >> 5);
      const int t = base_t + tl;
      const int bb = t & 7;
      const int ss = t >> 3;
      const int k = tidl & 31;
      float* xs = xs0 + grp * 16384;

      const int idx = sidx[tl * 32 + k];
      const float qx = snx[tl * 4 + 0];
      const float qy = snx[tl * 4 + 1];
      const float qz = snx[tl * 4 + 2];
      const float* pp = pos + ((size_t)bb * NPTS + idx) * 3;
      const float x0 = __fsub_rn(pp[0], qx);
      const float x1 = __fsub_rn(pp[1], qy);
      const float x2 = __fsub_rn(pp[2], qz);

      const float4* fT = (const float4*)(featT + ((size_t)bb * NPTS + idx) * 64);
#pragma unroll
      for (int c4 = 0; c4 < 16; ++c4) {
        float4 v = fT[c4];
        xs[(c4 * 4 + 0) * 256 + tidl] = v.x;
        xs[(c4 * 4 + 1) * 256 + tidl] = v.y;
        xs[(c4 * 4 + 2) * 256 + tidl] = v.z;
        xs[(c4 * 4 + 3) * 256 + tidl] = v.w;
      }
      const float* wt0 = wT;
      const float* wt1 = wT + 67 * 64;
      const float* wt2 = wT + 67 * 64 + 64 * 64;
      float acc[64];
#pragma unroll
      for (int o = 0; o < 64; ++o) acc[o] = b0[o];
      {
        const float4* wr;
        wr = (const float4*)(wt0 + 0 * 64); MLP_FMA16(wr, x0, acc);
        wr = (const float4*)(wt0 + 1 * 64); MLP_FMA16(wr, x1, acc);
        wr = (const float4*)(wt0 + 2 * 64); MLP_FMA16(wr, x2, acc);
      }
      for (int c = 0; c < 64; ++c) {
        float xc = xs[c * 256 + tidl];
        const float4* wr = (const float4*)(wt0 + (3 + c) * 64);
        MLP_FMA16(wr, xc, acc);
      }
#pragma unroll
      for (int o = 0; o < 64; ++o) xs[o * 256 + tidl] = fmaxf(acc[o], 0.0f);
#pragma unroll
      for (int o = 0; o < 64; ++o) acc[o] = b1[o];
      for (int c = 0; c < 64; ++c) {
        float xc = xs[c * 256 + tidl];
        const float4* wr = (const float4*)(wt1 + c * 64);
        MLP_FMA16(wr, xc, acc);
      }
#pragma unroll
      for (int o = 0; o < 64; ++o) xs[o * 256 + tidl] = fmaxf(acc[o], 0.0f);
#pragma unroll
      for (int h = 0; h < 2; ++h) {
#pragma unroll
        for (int o = 0; o < 64; ++o) acc[o] = b2[h * 64 + o];
        for (int c = 0; c < 64; ++c) {
          float xc = xs[c * 256 + tidl];
          const float4* wr = (const float4*)(wt2 + c * 128 + h * 64);
          MLP_FMA16(wr, xc, acc);
        }
#pragma unroll
        for (int o = 0; o < 64; ++o) {
          float v = fmaxf(acc[o], 0.0f);
          v = fmaxf(v, __shfl_xor(v, 16, 64));
          v = fmaxf(v, __shfl_xor(v, 8, 64));
          v = fmaxf(v, __shfl_xor(v, 4, 64));
          v = fmaxf(v, __shfl_xor(v, 2, 64));
          v = fmaxf(v, __shfl_xor(v, 1, 64));
          if ((tidl & 31) == 0)
            outf[((size_t)bb * 128 + h * 64 + o) * NS + ss] = v;
        }
      }
    }
    __syncthreads();  // xs/sidx reuse next round
  }
}

// ---------------------------------------------------------------------------
extern "C" void kernel_launch(void* const* d_in, const int* in_sizes, int n_in,
                              void* d_out, int out_size, void* d_ws,
                              size_t ws_size, hipStream_t stream) {
  const float* pos = (const float*)d_in[0];
  const float* feat = (const float*)d_in[1];
  const float* w0 = (const float*)d_in[2];
  const float* b0 = (const float*)d_in[3];
  const float* w1 = (const float*)d_in[4];
  const float* b1 = (const float*)d_in[5];
  const float* w2 = (const float*)d_in[6];
  const float* b2 = (const float*)d_in[7];

  float* out = (float*)d_out;
  float* new_xyz = out;                         // (B, S, 3)
  float* new_feat = out + (size_t)NB * NS * 3;  // (B, 128, S)
  char* ws = (char*)d_ws;

  // transpose featT/wT + zero ctrl (stream-ordered before fused kernel)
  hipLaunchKernelGGL(k_tp, dim3(NB * (NPTS / 64) + 1), dim3(256), 0, stream,
                     feat, w0, w1, w2, ws);
  // fused: 8 FPS blocks + 248 worker blocks, all co-resident
  hipLaunchKernelGGL(k_fused, dim3(256), dim3(512), 0, stream, pos, b0, b1,
                     b2, ws, new_xyz, new_feat);
}